// Round 15
// baseline (17.995 us; speedup 1.0000x reference)
//
#include <hip/hip_runtime.h>

typedef float v2f __attribute__((ext_vector_type(2)));

namespace {

constexpr int H = 128, W = 128, NPIX = H * W;
constexpr double GAMMA_Wd = 3.3257199;
constexpr float GAM2 = (float)(GAMMA_Wd * GAMMA_Wd);
constexpr float VBIG  = 1e30f;    // var' sentinel for var==0 (incl. OOB pad)
constexpr float NHUGE = -1e38f;   // d!=0 punishment

// 2x16 pixel tile -> 512 blocks -> 2 independent blocks/CU so one block's
// staging overlaps the other's compute (1-block/CU serialized all phases).
constexpr int TR = 2, TC = 16;
constexpr int HR = TR + 4, HC = TC + 4;   // 6 x 20
constexpr int NSITE = HR * HC;            // 120
constexpr int NK = 18;   // 9 guid*sqrt(sig/2*log2e) | 3 est | 3 var' | 3 noisy
constexpr int KP = 19;   // padded site stride in float4
constexpr int PXB = TR * TC;              // 32 px per block
constexpr int NSL = 8;                    // column-slices (half-wave each)
constexpr int NTHR = PXB * NSL;           // 256

constexpr double S2LOG2E = 1.2011224087864498;   // sqrt(log2(e))
constexpr float SCA0 = (float)(0.22360679774997896 * S2LOG2E);
constexpr float SCA1 = (float)(5.0                 * S2LOG2E);
constexpr float SCA2 = (float)(2.2360679774997896  * S2LOG2E);

__device__ __forceinline__ void column_body(
    const float4* __restrict__ js,
    const v2f gcc[9][2], const v2f nqc[2],
    const v2f eiP[3][2], const v2f viP[3][2],
    v2f accP[3][2], v2f denP[2])
{
    // guidance quadratic (packed over t)
    v2f qj2[2] = {};
    v2f cr[4][2] = {};            // cross[tt][t-half]
#pragma unroll
    for (int c = 0; c < 9; ++c) {
        const float4 g = js[c];
        const v2f g01 = (v2f){g.x, g.y}, g23 = (v2f){g.z, g.w};
        qj2[0] += g01 * g01;  qj2[1] += g23 * g23;
        cr[0][0] += gcc[c][0] * g.x;  cr[0][1] += gcc[c][1] * g.x;
        cr[1][0] += gcc[c][0] * g.y;  cr[1][1] += gcc[c][1] * g.y;
        cr[2][0] += gcc[c][0] * g.z;  cr[2][1] += gcc[c][1] * g.z;
        cr[3][0] += gcc[c][0] * g.w;  cr[3][1] += gcc[c][1] * g.w;
    }

    // membership (pure arithmetic): rf = max(S'-d^2, NHUGE*d^2); pass <=> min_c rf >= 0
    v2f rm[4][2];
#pragma unroll
    for (int c = 0; c < 3; ++c) {
        const float4 e4 = js[9 + c];
        const float4 w4 = js[12 + c];
        const float ejs[4] = {e4.x, e4.y, e4.z, e4.w};
        const float vjs[4] = {w4.x, w4.y, w4.z, w4.w};
#pragma unroll
        for (int tt = 0; tt < 4; ++tt) {
#pragma unroll
            for (int hf = 0; hf < 2; ++hf) {
                const v2f d  = eiP[c][hf] - ejs[tt];
                const v2f S  = viP[c][hf] + vjs[tt];
                const v2f dd = d * d;
                const v2f r  = S - dd;
                const v2f z  = dd * NHUGE;
                const v2f rf = __builtin_elementwise_max(r, z);
                rm[tt][hf] = (c == 0) ? rf
                           : __builtin_elementwise_min(rm[tt][hf], rf);
            }
        }
    }

    // weights + accumulate (exp2 domain)
    v2f f01[4], f23[4];
#pragma unroll
    for (int tt = 0; tt < 4; ++tt) {
        const float qjt = qj2[tt >> 1][tt & 1];
        const v2f a0 = cr[tt][0] * 2.f + (nqc[0] - qjt);
        const v2f a1 = cr[tt][1] * 2.f + (nqc[1] - qjt);
        float fv[4];
#pragma unroll
        for (int t = 0; t < 4; ++t) {
            const bool valid = (tt - t <= 2) && (t - tt <= 2);
            if (valid) {
                const float av = (t < 2) ? a0[t & 1] : a1[t & 1];
                const float rv = (t < 2) ? rm[tt][0][t & 1] : rm[tt][1][t & 1];
                const float e  = __builtin_exp2f(av);
                fv[t] = (rv >= 0.f) ? e : 0.f;
            } else {
                fv[t] = 0.f;
            }
        }
        f01[tt] = (v2f){fv[0], fv[1]};
        f23[tt] = (v2f){fv[2], fv[3]};
        denP[0] += f01[tt];
        denP[1] += f23[tt];
    }
#pragma unroll
    for (int c = 0; c < 3; ++c) {
        const float4 n4 = js[15 + c];
        const float njs[4] = {n4.x, n4.y, n4.z, n4.w};
#pragma unroll
        for (int tt = 0; tt < 4; ++tt) {
            accP[c][0] += f01[tt] * njs[tt];
            accP[c][1] += f23[tt] * njs[tt];
        }
    }
}

__global__ __launch_bounds__(NTHR)
__attribute__((amdgpu_waves_per_eu(2, 8)))   // proven no-spill combo (R9)
void statden(const float4* __restrict__ noisy,
             const float4* __restrict__ guid,
             const float4* __restrict__ est,
             const float4* __restrict__ var,
             float4* __restrict__ out)
{
    __shared__ float4 halo[NSITE * KP];   // 36480 B; reused as reduce scratch

    const int tid   = threadIdx.x;
    const int tiler = blockIdx.x >> 3;    // 0..63 (row tiles of height 2)
    const int tilec = blockIdx.x & 7;
    const int r0 = tiler * TR - 2;
    const int c0 = tilec * TC - 2;

    // ---- stage halo (transforms folded; zero-pad OOB == reference padding) ----
    for (int u = tid; u < NSITE * NK; u += NTHR) {
        const int k    = u / NSITE;
        const int site = u - k * NSITE;
        const int sr  = site / HC;
        const int scp = site - sr * HC;
        const int gr = r0 + sr;
        const int gc = c0 + scp;
        const bool varslot = (k >= 12) && (k < 15);
        float4 v;
        if (((unsigned)gr < (unsigned)H) && ((unsigned)gc < (unsigned)W)) {
            const int gpix = (gr << 7) + gc;
            if (k < 9) {
                const float sca = (k < 3) ? SCA0 : (k < 6) ? SCA1 : SCA2;
                const float4 g = guid[k * NPIX + gpix];
                v = make_float4(g.x * sca, g.y * sca, g.z * sca, g.w * sca);
            } else if (k < 12) {
                v = est[(k - 9) * NPIX + gpix];
            } else if (k < 15) {
                const float4 w4 = var[(k - 12) * NPIX + gpix];
                v.x = (w4.x == 0.f) ? -VBIG : GAM2 * w4.x;
                v.y = (w4.y == 0.f) ? -VBIG : GAM2 * w4.y;
                v.z = (w4.z == 0.f) ? -VBIG : GAM2 * w4.z;
                v.w = (w4.w == 0.f) ? -VBIG : GAM2 * w4.w;
            } else {
                v = noisy[(k - 15) * NPIX + gpix];
            }
        } else {
            const float pad = varslot ? -VBIG : 0.f;
            v = make_float4(pad, pad, pad, pad);
        }
        halo[site * KP + k] = v;
    }
    __syncthreads();

    // ---- compute: thread = (pixel p in 0..31, slice s in 0..7) ----
    const int p  = tid & (PXB - 1);
    const int s  = tid >> 5;              // slice = half-wave
    const int pr = p >> 4;                // 0..1
    const int pc = p & 15;

    const float4* cs = &halo[((pr + 2) * HC + (pc + 2)) * KP];

    v2f gcc[9][2];
    v2f nqc[2] = {{0.f, 0.f}, {0.f, 0.f}};   // -qc~ (log2 units)
#pragma unroll
    for (int c = 0; c < 9; ++c) {
        const float4 g = cs[c];
        gcc[c][0] = (v2f){g.x, g.y};
        gcc[c][1] = (v2f){g.z, g.w};
        nqc[0] -= gcc[c][0] * gcc[c][0];
        nqc[1] -= gcc[c][1] * gcc[c][1];
    }
    v2f eiP[3][2], viP[3][2];
#pragma unroll
    for (int c = 0; c < 3; ++c) {
        const float4 e = cs[9 + c];
        eiP[c][0] = (v2f){e.x, e.y}; eiP[c][1] = (v2f){e.z, e.w};
        const float4 w4 = cs[12 + c];
        viP[c][0] = (v2f){w4.x, w4.y}; viP[c][1] = (v2f){w4.z, w4.w};
    }

    v2f accP[3][2] = {};
    v2f denP[2] = {};

    // slice s owns 3 non-center columns; s==7 additionally runs the center.
#pragma unroll
    for (int mm = 0; mm < 3; ++mm) {
        const int m   = s * 3 + mm;
        const int col = m + (m >= 12 ? 1 : 0);   // skip center (col 12)
        const int di  = col / 5 - 2;
        const int dj  = col - (col / 5) * 5 - 2;
        const float4* js = &halo[((pr + 2 + di) * HC + (pc + 2 + dj)) * KP];
        column_body(js, gcc, nqc, eiP, viP, accP, denP);
    }
    if (s == 7) {                          // center column (di=dj=0)
        column_body(cs, gcc, nqc, eiP, viP, accP, denP);
    }

    // ---- reduce 8 slices; reuse halo LDS as float scratch (stride 17) ----
    __syncthreads();                       // all halo reads complete before overwrite
    float* red = reinterpret_cast<float*>(halo);
    {
        float* r = red + (s * PXB + p) * 17;
#pragma unroll
        for (int c = 0; c < 3; ++c) {
            r[c * 4 + 0] = accP[c][0][0]; r[c * 4 + 1] = accP[c][0][1];
            r[c * 4 + 2] = accP[c][1][0]; r[c * 4 + 3] = accP[c][1][1];
        }
        r[12] = denP[0][0]; r[13] = denP[0][1];
        r[14] = denP[1][0]; r[15] = denP[1][1];
    }
    __syncthreads();

    if (tid < PXB) {                       // s==0: centers here are this pixel's
        float v[16];
        const float* rp = red + p * 17;
#pragma unroll
        for (int i = 0; i < 16; ++i) v[i] = rp[i];
#pragma unroll
        for (int k = 1; k < NSL; ++k) {
            const float* rk = red + (k * PXB + p) * 17;
#pragma unroll
            for (int i = 0; i < 16; ++i) v[i] += rk[i];
        }

        // t-axis zero-padded patches: {2,1,1,2} dk-OOB per t, x25 offsets.
        const float cnt[4] = {50.f, 25.f, 25.f, 50.f};
        const float qn[4]  = {nqc[0][0], nqc[0][1], nqc[1][0], nqc[1][1]};
        const float e0[4]  = {eiP[0][0][0], eiP[0][0][1], eiP[0][1][0], eiP[0][1][1]};
        const float e1[4]  = {eiP[1][0][0], eiP[1][0][1], eiP[1][1][0], eiP[1][1][1]};
        const float e2[4]  = {eiP[2][0][0], eiP[2][0][1], eiP[2][1][0], eiP[2][1][1]};
#pragma unroll
        for (int t = 0; t < 4; ++t) {
            const bool allz = (e0[t] == 0.f) && (e1[t] == 0.f) && (e2[t] == 0.f);
            const float f0 = allz ? __builtin_exp2f(qn[t]) : 0.f;
            v[12 + t] += cnt[t] * f0;
        }

#pragma unroll
        for (int t = 0; t < 4; ++t) {
            const float inv = 1.f / fmaxf(v[12 + t], 1e-12f);
            v[0 + t] *= inv; v[4 + t] *= inv; v[8 + t] *= inv;
        }
        const int pid = ((tiler * TR + pr) << 7) + tilec * TC + pc;
#pragma unroll
        for (int c = 0; c < 3; ++c) {
            float4 o;
            o.x = v[c * 4 + 0]; o.y = v[c * 4 + 1];
            o.z = v[c * 4 + 2]; o.w = v[c * 4 + 3];
            out[c * NPIX + pid] = o;
        }
    }
}

} // namespace

extern "C" void kernel_launch(void* const* d_in, const int* in_sizes, int n_in,
                              void* d_out, int out_size, void* d_ws, size_t ws_size,
                              hipStream_t stream)
{
    const float4* noisy = (const float4*)d_in[0];
    const float4* guid  = (const float4*)d_in[1];
    const float4* est   = (const float4*)d_in[2];
    const float4* var   = (const float4*)d_in[3];
    float4* out = (float4*)d_out;

    statden<<<(H / TR) * (W / TC), NTHR, 0, stream>>>(noisy, guid, est, var, out);
}

// Round 16
// 15.533 us; speedup vs baseline: 1.1585x; 1.1585x over previous
//
#include <hip/hip_runtime.h>

typedef float v2f __attribute__((ext_vector_type(2)));

namespace {

constexpr int H = 128, W = 128, NPIX = H * W;
constexpr double GAMMA_Wd = 3.3257199;
constexpr float GAM2 = (float)(GAMMA_Wd * GAMMA_Wd);
constexpr float VBIG  = 1e30f;    // var' sentinel for var==0 (incl. OOB pad)
constexpr float NHUGE = -1e38f;   // d!=0 punishment

constexpr int TR = 4, TC = 16;
constexpr int HR = TR + 4, HC = TC + 4;   // 8 x 20
constexpr int NSITE = HR * HC;            // 160
constexpr int NK = 18;   // 9 guid*sqrt(sig/2*log2e) | 3 est | 3 var' | 3 noisy
constexpr int KP = 19;   // padded site stride in float4
constexpr int NSL = 8;
constexpr int NTHR = 64 * NSL;            // 512 (R9 geometry: best known, 15.0us)

constexpr double S2LOG2E = 1.2011224087864498;   // sqrt(log2(e))
constexpr float SCA0 = (float)(0.22360679774997896 * S2LOG2E);
constexpr float SCA1 = (float)(5.0                 * S2LOG2E);
constexpr float SCA2 = (float)(2.2360679774997896  * S2LOG2E);

// Quarter body: column 24 (di=2,dj=2), single source slice tt=Q.
// ~0.3 of a full body: 18 scalar ds_read_b32 + ~85 VALU ops.
template<int Q>
__device__ __forceinline__ void quarter_body(
    const float* __restrict__ jf,           // scalar view of col-24 site
    const v2f gcc[9][2], const v2f nqc[2],
    const v2f eiP[3][2], const v2f viP[3][2],
    v2f accP[3][2], v2f denP[2])
{
    float qjq = 0.f;
    v2f cr0 = {0.f, 0.f}, cr1 = {0.f, 0.f};
#pragma unroll
    for (int c = 0; c < 9; ++c) {
        const float g = jf[c * 4 + Q];
        qjq += g * g;
        cr0 += gcc[c][0] * g;
        cr1 += gcc[c][1] * g;
    }

    v2f rm0, rm1;
#pragma unroll
    for (int c = 0; c < 3; ++c) {
        const float ej = jf[(9 + c) * 4 + Q];
        const float vj = jf[(12 + c) * 4 + Q];
        {
            const v2f d  = eiP[c][0] - ej;
            const v2f S  = viP[c][0] + vj;
            const v2f dd = d * d;
            const v2f rf = __builtin_elementwise_max(S - dd, dd * NHUGE);
            rm0 = (c == 0) ? rf : __builtin_elementwise_min(rm0, rf);
        }
        {
            const v2f d  = eiP[c][1] - ej;
            const v2f S  = viP[c][1] + vj;
            const v2f dd = d * d;
            const v2f rf = __builtin_elementwise_max(S - dd, dd * NHUGE);
            rm1 = (c == 0) ? rf : __builtin_elementwise_min(rm1, rf);
        }
    }

    const v2f a0 = cr0 * 2.f + (nqc[0] - qjq);
    const v2f a1 = cr1 * 2.f + (nqc[1] - qjq);
    float fv[4];
#pragma unroll
    for (int t = 0; t < 4; ++t) {
        const bool valid = (Q - t <= 2) && (t - Q <= 2);
        if (valid) {
            const float av = (t < 2) ? a0[t & 1] : a1[t & 1];
            const float rv = (t < 2) ? rm0[t & 1] : rm1[t & 1];
            fv[t] = (rv >= 0.f) ? __builtin_exp2f(av) : 0.f;
        } else {
            fv[t] = 0.f;
        }
    }
    const v2f f01 = (v2f){fv[0], fv[1]};
    const v2f f23 = (v2f){fv[2], fv[3]};
    denP[0] += f01;
    denP[1] += f23;
#pragma unroll
    for (int c = 0; c < 3; ++c) {
        const float nj = jf[(15 + c) * 4 + Q];
        accP[c][0] += f01 * nj;
        accP[c][1] += f23 * nj;
    }
}

__global__ __launch_bounds__(NTHR)
__attribute__((amdgpu_waves_per_eu(2, 8)))   // proven no-spill combo (R9/R12)
void statden(const float4* __restrict__ noisy,
             const float4* __restrict__ guid,
             const float4* __restrict__ est,
             const float4* __restrict__ var,
             float4* __restrict__ out)
{
    __shared__ float4 halo[NSITE * KP];   // 48640 B; reused as reduce scratch

    const int tid   = threadIdx.x;
    const int tiler = blockIdx.x >> 3;
    const int tilec = blockIdx.x & 7;
    const int r0 = tiler * TR - 2;
    const int c0 = tilec * TC - 2;

    // ---- stage halo (transforms folded; zero-pad OOB == reference padding) ----
    for (int u = tid; u < NSITE * NK; u += NTHR) {
        const int k    = u / NSITE;
        const int site = u - k * NSITE;
        const int sr  = site / HC;
        const int scp = site - sr * HC;
        const int gr = r0 + sr;
        const int gc = c0 + scp;
        const bool varslot = (k >= 12) && (k < 15);
        float4 v;
        if (((unsigned)gr < (unsigned)H) && ((unsigned)gc < (unsigned)W)) {
            const int gpix = (gr << 7) + gc;
            if (k < 9) {
                const float sca = (k < 3) ? SCA0 : (k < 6) ? SCA1 : SCA2;
                const float4 g = guid[k * NPIX + gpix];
                v = make_float4(g.x * sca, g.y * sca, g.z * sca, g.w * sca);
            } else if (k < 12) {
                v = est[(k - 9) * NPIX + gpix];
            } else if (k < 15) {
                const float4 w4 = var[(k - 12) * NPIX + gpix];
                v.x = (w4.x == 0.f) ? -VBIG : GAM2 * w4.x;
                v.y = (w4.y == 0.f) ? -VBIG : GAM2 * w4.y;
                v.z = (w4.z == 0.f) ? -VBIG : GAM2 * w4.z;
                v.w = (w4.w == 0.f) ? -VBIG : GAM2 * w4.w;
            } else {
                v = noisy[(k - 15) * NPIX + gpix];
            }
        } else {
            const float pad = varslot ? -VBIG : 0.f;
            v = make_float4(pad, pad, pad, pad);
        }
        halo[site * KP + k] = v;
    }
    __syncthreads();

    // ---- compute: thread = (pixel p, slice s) ----
    const int p  = tid & 63;
    const int s  = tid >> 6;              // 0..7, wave-uniform
    const int pr = p >> 4;
    const int pc = p & 15;

    const float4* cs = &halo[((pr + 2) * HC + (pc + 2)) * KP];

    v2f gcc[9][2];
    v2f nqc[2] = {{0.f, 0.f}, {0.f, 0.f}};   // -qc~ (log2 units)
#pragma unroll
    for (int c = 0; c < 9; ++c) {
        const float4 g = cs[c];
        gcc[c][0] = (v2f){g.x, g.y};
        gcc[c][1] = (v2f){g.z, g.w};
        nqc[0] -= gcc[c][0] * gcc[c][0];
        nqc[1] -= gcc[c][1] * gcc[c][1];
    }
    v2f eiP[3][2], viP[3][2];
#pragma unroll
    for (int c = 0; c < 3; ++c) {
        const float4 e = cs[9 + c];
        eiP[c][0] = (v2f){e.x, e.y}; eiP[c][1] = (v2f){e.z, e.w};
        const float4 w4 = cs[12 + c];
        viP[c][0] = (v2f){w4.x, w4.y}; viP[c][1] = (v2f){w4.z, w4.w};
    }

    v2f accP[3][2] = {};
    v2f denP[2] = {};

    // CRITICAL-PATH FLATTENING: every wave runs exactly 3 full bodies over
    // cols 0..23 ({s, s+8, s+16}; center col 12 is an ordinary body), and
    // col 24 (di=2,dj=2) is split tt-quarter-wise across waves 0..3 (~0.3
    // body each). R9's map gave wave 0 a 4th full body = the block critical
    // path all barriers waited on.
#pragma unroll
    for (int mm = 0; mm < 3; ++mm) {
        const int col = s + (mm << 3);    // 0..23
        const int di  = col / 5 - 2;
        const int dj  = col - (col / 5) * 5 - 2;
        const float4* js = &halo[((pr + 2 + di) * HC + (pc + 2 + dj)) * KP];

        // guidance quadratic (packed over t)
        v2f qj2[2] = {};
        v2f cr[4][2] = {};
#pragma unroll
        for (int c = 0; c < 9; ++c) {
            const float4 g = js[c];
            const v2f g01 = (v2f){g.x, g.y}, g23 = (v2f){g.z, g.w};
            qj2[0] += g01 * g01;  qj2[1] += g23 * g23;
            cr[0][0] += gcc[c][0] * g.x;  cr[0][1] += gcc[c][1] * g.x;
            cr[1][0] += gcc[c][0] * g.y;  cr[1][1] += gcc[c][1] * g.y;
            cr[2][0] += gcc[c][0] * g.z;  cr[2][1] += gcc[c][1] * g.z;
            cr[3][0] += gcc[c][0] * g.w;  cr[3][1] += gcc[c][1] * g.w;
        }

        // membership: rf = max(S'-d^2, NHUGE*d^2); pass <=> min_c rf >= 0
        v2f rm[4][2];
#pragma unroll
        for (int c = 0; c < 3; ++c) {
            const float4 e4 = js[9 + c];
            const float4 w4 = js[12 + c];
            const float ejs[4] = {e4.x, e4.y, e4.z, e4.w};
            const float vjs[4] = {w4.x, w4.y, w4.z, w4.w};
#pragma unroll
            for (int tt = 0; tt < 4; ++tt) {
#pragma unroll
                for (int hf = 0; hf < 2; ++hf) {
                    const v2f d  = eiP[c][hf] - ejs[tt];
                    const v2f S  = viP[c][hf] + vjs[tt];
                    const v2f dd = d * d;
                    const v2f rf = __builtin_elementwise_max(S - dd, dd * NHUGE);
                    rm[tt][hf] = (c == 0) ? rf
                               : __builtin_elementwise_min(rm[tt][hf], rf);
                }
            }
        }

        // weights + accumulate (exp2 domain)
        v2f f01[4], f23[4];
#pragma unroll
        for (int tt = 0; tt < 4; ++tt) {
            const float qjt = qj2[tt >> 1][tt & 1];
            const v2f a0 = cr[tt][0] * 2.f + (nqc[0] - qjt);
            const v2f a1 = cr[tt][1] * 2.f + (nqc[1] - qjt);
            float fv[4];
#pragma unroll
            for (int t = 0; t < 4; ++t) {
                const bool valid = (tt - t <= 2) && (t - tt <= 2);
                if (valid) {
                    const float av = (t < 2) ? a0[t & 1] : a1[t & 1];
                    const float rv = (t < 2) ? rm[tt][0][t & 1] : rm[tt][1][t & 1];
                    fv[t] = (rv >= 0.f) ? __builtin_exp2f(av) : 0.f;
                } else {
                    fv[t] = 0.f;
                }
            }
            f01[tt] = (v2f){fv[0], fv[1]};
            f23[tt] = (v2f){fv[2], fv[3]};
            denP[0] += f01[tt];
            denP[1] += f23[tt];
        }
#pragma unroll
        for (int c = 0; c < 3; ++c) {
            const float4 n4 = js[15 + c];
            const float njs[4] = {n4.x, n4.y, n4.z, n4.w};
#pragma unroll
            for (int tt = 0; tt < 4; ++tt) {
                accP[c][0] += f01[tt] * njs[tt];
                accP[c][1] += f23[tt] * njs[tt];
            }
        }
    }

    // col 24 quarter, waves 0..3 only (wave-uniform branches, compile-time Q)
    {
        const float* jf = reinterpret_cast<const float*>(
            &halo[((pr + 4) * HC + (pc + 4)) * KP]);
        if (s == 0) quarter_body<0>(jf, gcc, nqc, eiP, viP, accP, denP);
        else if (s == 1) quarter_body<1>(jf, gcc, nqc, eiP, viP, accP, denP);
        else if (s == 2) quarter_body<2>(jf, gcc, nqc, eiP, viP, accP, denP);
        else if (s == 3) quarter_body<3>(jf, gcc, nqc, eiP, viP, accP, denP);
    }

    // ---- reduce 8 slices; reuse halo LDS as float scratch (stride 17) ----
    __syncthreads();
    float* red = reinterpret_cast<float*>(halo);
    {
        float* r = red + (s * 64 + p) * 17;
#pragma unroll
        for (int c = 0; c < 3; ++c) {
            r[c * 4 + 0] = accP[c][0][0]; r[c * 4 + 1] = accP[c][0][1];
            r[c * 4 + 2] = accP[c][1][0]; r[c * 4 + 3] = accP[c][1][1];
        }
        r[12] = denP[0][0]; r[13] = denP[0][1];
        r[14] = denP[1][0]; r[15] = denP[1][1];
    }
    __syncthreads();

    if (tid < 64) {                        // s==0: centers here are this pixel's
        float v[16];
        const float* rp = red + p * 17;
#pragma unroll
        for (int i = 0; i < 16; ++i) v[i] = rp[i];
#pragma unroll
        for (int k = 1; k < NSL; ++k) {
            const float* rk = red + (k * 64 + p) * 17;
#pragma unroll
            for (int i = 0; i < 16; ++i) v[i] += rk[i];
        }

        // t-axis zero-padded patches: {2,1,1,2} dk-OOB per t, x25 offsets.
        const float cnt[4] = {50.f, 25.f, 25.f, 50.f};
        const float qn[4]  = {nqc[0][0], nqc[0][1], nqc[1][0], nqc[1][1]};
        const float e0[4]  = {eiP[0][0][0], eiP[0][0][1], eiP[0][1][0], eiP[0][1][1]};
        const float e1[4]  = {eiP[1][0][0], eiP[1][0][1], eiP[1][1][0], eiP[1][1][1]};
        const float e2[4]  = {eiP[2][0][0], eiP[2][0][1], eiP[2][1][0], eiP[2][1][1]};
#pragma unroll
        for (int t = 0; t < 4; ++t) {
            const bool allz = (e0[t] == 0.f) && (e1[t] == 0.f) && (e2[t] == 0.f);
            const float f0 = allz ? __builtin_exp2f(qn[t]) : 0.f;
            v[12 + t] += cnt[t] * f0;
        }

#pragma unroll
        for (int t = 0; t < 4; ++t) {
            const float inv = 1.f / fmaxf(v[12 + t], 1e-12f);
            v[0 + t] *= inv; v[4 + t] *= inv; v[8 + t] *= inv;
        }
        const int pid = ((tiler * TR + pr) << 7) + tilec * TC + pc;
#pragma unroll
        for (int c = 0; c < 3; ++c) {
            float4 o;
            o.x = v[c * 4 + 0]; o.y = v[c * 4 + 1];
            o.z = v[c * 4 + 2]; o.w = v[c * 4 + 3];
            out[c * NPIX + pid] = o;
        }
    }
}

} // namespace

extern "C" void kernel_launch(void* const* d_in, const int* in_sizes, int n_in,
                              void* d_out, int out_size, void* d_ws, size_t ws_size,
                              hipStream_t stream)
{
    const float4* noisy = (const float4*)d_in[0];
    const float4* guid  = (const float4*)d_in[1];
    const float4* est   = (const float4*)d_in[2];
    const float4* var   = (const float4*)d_in[3];
    float4* out = (float4*)d_out;

    statden<<<(H / TR) * (W / TC), NTHR, 0, stream>>>(noisy, guid, est, var, out);
}

// Round 17
// 15.299 us; speedup vs baseline: 1.1762x; 1.0153x over previous
//
#include <hip/hip_runtime.h>

typedef float v2f __attribute__((ext_vector_type(2)));

namespace {

constexpr int H = 128, W = 128, NPIX = H * W;
constexpr double GAMMA_Wd = 3.3257199;
constexpr float GAM2 = (float)(GAMMA_Wd * GAMMA_Wd);
constexpr float VBIG  = 1e30f;    // var' sentinel for var==0
constexpr float NHUGE = -1e38f;   // d!=0 punishment

constexpr int NSL = 8;
constexpr int NTHR = 512;         // 64 px x 8 slices (R9 geometry)

// sigma'' = sigma * log2(e) / 2  (exp2-domain Gaussian)
constexpr double L2E2 = 0.7213475204444817;
constexpr float SG0 = (float)(0.1 * L2E2);
constexpr float SG1 = (float)(50.0 * L2E2);
constexpr float SG2 = (float)(10.0 * L2E2);

// NO HALO: inputs are 4.6 MB (fully L2-resident; ~46 KB/block ~ L1-scale).
// R8/R9's LDS staging was pure overhead: per-CU LDS pipe (8 waves x 54
// ds_read_b128 x ~12cy ~ 5200 cy) + stage phase + barrier was the binding
// resource no TLP/structure experiment touched (rounds 10-16 all null).
// Columns read straight from global: 64 consecutive pixels/wave -> 1 KB
// coalesced segments. Spatial-OOB columns skipped per-lane and folded into
// the closed-form epilogue (R2-proven: oob = 125 - nh*nw*ntt[t]).
__global__ __launch_bounds__(NTHR)
__attribute__((amdgpu_waves_per_eu(2, 8)))   // proven no-spill combo
void statden(const float4* __restrict__ noisy,
             const float4* __restrict__ guid,
             const float4* __restrict__ est,
             const float4* __restrict__ var,
             float4* __restrict__ out)
{
    __shared__ float red[NSL * 64 * 17];   // 34816 B: reduce scratch only

    const int tid = threadIdx.x;
    const int p   = tid & 63;
    const int s   = tid >> 6;             // 0..7, wave-uniform
    const int h   = blockIdx.x >> 1;      // block = half image row: h uniform
    const int w   = ((blockIdx.x & 1) << 6) + p;
    const int pid = (h << 7) + w;

    const float sgl[9] = {SG0, SG0, SG0, SG1, SG1, SG1, SG2, SG2, SG2};

    // ---- centers (global, coalesced) ----
    v2f gcd[9][2];                        // 2*sigma''*gc
    v2f nqc[2] = {{0.f, 0.f}, {0.f, 0.f}};   // -sum sigma''*gc^2 (log2 units)
#pragma unroll
    for (int c = 0; c < 9; ++c) {
        const float4 g = guid[c * NPIX + pid];
        const v2f g01 = (v2f){g.x, g.y}, g23 = (v2f){g.z, g.w};
        const v2f t0 = g01 * sgl[c], t1 = g23 * sgl[c];
        nqc[0] -= t0 * g01;
        nqc[1] -= t1 * g23;
        gcd[c][0] = t0 * 2.f;
        gcd[c][1] = t1 * 2.f;
    }
    v2f eiP[3][2], viP[3][2];
#pragma unroll
    for (int c = 0; c < 3; ++c) {
        const float4 e = est[c * NPIX + pid];
        eiP[c][0] = (v2f){e.x, e.y}; eiP[c][1] = (v2f){e.z, e.w};
        const float4 vv = var[c * NPIX + pid];
        const float v0 = (vv.x == 0.f) ? -VBIG : GAM2 * vv.x;
        const float v1 = (vv.y == 0.f) ? -VBIG : GAM2 * vv.y;
        const float v2 = (vv.z == 0.f) ? -VBIG : GAM2 * vv.z;
        const float v3 = (vv.w == 0.f) ? -VBIG : GAM2 * vv.w;
        viP[c][0] = (v2f){v0, v1}; viP[c][1] = (v2f){v2, v3};
    }

    v2f accP[3][2] = {};
    v2f denP[2] = {};

    // R9 column map: slice s owns {s, s+8, s+16}; s==0 additionally col 24.
#pragma unroll
    for (int mm = 0; mm < 4; ++mm) {
        if (mm == 3 && s != 0) continue;  // wave-uniform
        const int col = (mm == 3) ? 24 : (s + (mm << 3));
        const int di  = col / 5 - 2;
        const int dj  = col - (col / 5) * 5 - 2;
        const int hh  = h + di;
        if ((unsigned)hh >= (unsigned)H) continue;   // block-uniform
        const int ww  = w + dj;
        if ((unsigned)ww >= (unsigned)W) continue;   // per-lane (2 edge lanes)
        const int q = (hh << 7) + ww;

        // guidance quadratic (sigma'' folded in-body; cross pre-doubled via gcd)
        v2f qj2[2] = {};
        v2f cr[4][2] = {};                // cross*2 [tt][t-half]
#pragma unroll
        for (int c = 0; c < 9; ++c) {
            const float4 g = guid[c * NPIX + q];
            const v2f g01 = (v2f){g.x, g.y}, g23 = (v2f){g.z, g.w};
            qj2[0] += (g01 * sgl[c]) * g01;
            qj2[1] += (g23 * sgl[c]) * g23;
            cr[0][0] += gcd[c][0] * g.x;  cr[0][1] += gcd[c][1] * g.x;
            cr[1][0] += gcd[c][0] * g.y;  cr[1][1] += gcd[c][1] * g.y;
            cr[2][0] += gcd[c][0] * g.z;  cr[2][1] += gcd[c][1] * g.z;
            cr[3][0] += gcd[c][0] * g.w;  cr[3][1] += gcd[c][1] * g.w;
        }

        // membership: rf = max((vi'+vj') - d^2, d^2*NHUGE); pass <=> min_c rf >= 0
        v2f rm[4][2];
#pragma unroll
        for (int c = 0; c < 3; ++c) {
            const float4 e4 = est[c * NPIX + q];
            const float4 w4 = var[c * NPIX + q];
            const float ejs[4] = {e4.x, e4.y, e4.z, e4.w};
            float vjp[4];
            vjp[0] = (w4.x == 0.f) ? -VBIG : GAM2 * w4.x;
            vjp[1] = (w4.y == 0.f) ? -VBIG : GAM2 * w4.y;
            vjp[2] = (w4.z == 0.f) ? -VBIG : GAM2 * w4.z;
            vjp[3] = (w4.w == 0.f) ? -VBIG : GAM2 * w4.w;
#pragma unroll
            for (int tt = 0; tt < 4; ++tt) {
#pragma unroll
                for (int hf = 0; hf < 2; ++hf) {
                    const v2f d  = eiP[c][hf] - ejs[tt];
                    const v2f S  = viP[c][hf] + vjp[tt];
                    const v2f dd = d * d;
                    const v2f rf = __builtin_elementwise_max(S - dd, dd * NHUGE);
                    rm[tt][hf] = (c == 0) ? rf
                               : __builtin_elementwise_min(rm[tt][hf], rf);
                }
            }
        }

        // weights + accumulate (exp2 domain)
        v2f f01[4], f23[4];
#pragma unroll
        for (int tt = 0; tt < 4; ++tt) {
            const float qjt = qj2[tt >> 1][tt & 1];
            const v2f a0 = cr[tt][0] + (nqc[0] - qjt);
            const v2f a1 = cr[tt][1] + (nqc[1] - qjt);
            float fv[4];
#pragma unroll
            for (int t = 0; t < 4; ++t) {
                const bool valid = (tt - t <= 2) && (t - tt <= 2);
                if (valid) {
                    const float av = (t < 2) ? a0[t & 1] : a1[t & 1];
                    const float rv = (t < 2) ? rm[tt][0][t & 1] : rm[tt][1][t & 1];
                    fv[t] = (rv >= 0.f) ? __builtin_exp2f(av) : 0.f;
                } else {
                    fv[t] = 0.f;
                }
            }
            f01[tt] = (v2f){fv[0], fv[1]};
            f23[tt] = (v2f){fv[2], fv[3]};
            denP[0] += f01[tt];
            denP[1] += f23[tt];
        }
#pragma unroll
        for (int c = 0; c < 3; ++c) {
            const float4 n4 = noisy[c * NPIX + q];
            const float njs[4] = {n4.x, n4.y, n4.z, n4.w};
#pragma unroll
            for (int tt = 0; tt < 4; ++tt) {
                accP[c][0] += f01[tt] * njs[tt];
                accP[c][1] += f23[tt] * njs[tt];
            }
        }
    }

    // ---- reduce 8 slices (stride 17, conflict-free) ----
    {
        float* r = red + (s * 64 + p) * 17;
#pragma unroll
        for (int c = 0; c < 3; ++c) {
            r[c * 4 + 0] = accP[c][0][0]; r[c * 4 + 1] = accP[c][0][1];
            r[c * 4 + 2] = accP[c][1][0]; r[c * 4 + 3] = accP[c][1][1];
        }
        r[12] = denP[0][0]; r[13] = denP[0][1];
        r[14] = denP[1][0]; r[15] = denP[1][1];
    }
    __syncthreads();

    if (tid < 64) {                        // s==0: centers here are this pixel's
        float v[16];
        const float* rp = red + p * 17;
#pragma unroll
        for (int i = 0; i < 16; ++i) v[i] = rp[i];
#pragma unroll
        for (int k = 1; k < NSL; ++k) {
            const float* rk = red + (k * 64 + p) * 17;
#pragma unroll
            for (int i = 0; i < 16; ++i) v[i] += rk[i];
        }

        // zero-padded patches (spatial OOB any-t + t-axis OOB): R2-proven
        // closed form: oob = 125 - nh*nw*ntt[t]; member iff all ec==0;
        // bw = exp2(nqc) (log2 units).
        const int nh  = min(h + 2, H - 1) - max(h - 2, 0) + 1;
        const int nw  = min(w + 2, W - 1) - max(w - 2, 0) + 1;
        const int nhw = nh * nw;
        const int ntt[4] = {3, 4, 4, 3};
        const float qn[4] = {nqc[0][0], nqc[0][1], nqc[1][0], nqc[1][1]};
        const float e0[4] = {eiP[0][0][0], eiP[0][0][1], eiP[0][1][0], eiP[0][1][1]};
        const float e1[4] = {eiP[1][0][0], eiP[1][0][1], eiP[1][1][0], eiP[1][1][1]};
        const float e2[4] = {eiP[2][0][0], eiP[2][0][1], eiP[2][1][0], eiP[2][1][1]};
#pragma unroll
        for (int t = 0; t < 4; ++t) {
            const int oob = 125 - nhw * ntt[t];
            const bool allz = (e0[t] == 0.f) && (e1[t] == 0.f) && (e2[t] == 0.f);
            const float f0 = allz ? __builtin_exp2f(qn[t]) : 0.f;
            v[12 + t] += (float)oob * f0;
        }

#pragma unroll
        for (int t = 0; t < 4; ++t) {
            const float inv = 1.f / fmaxf(v[12 + t], 1e-12f);
            v[0 + t] *= inv; v[4 + t] *= inv; v[8 + t] *= inv;
        }
#pragma unroll
        for (int c = 0; c < 3; ++c) {
            float4 o;
            o.x = v[c * 4 + 0]; o.y = v[c * 4 + 1];
            o.z = v[c * 4 + 2]; o.w = v[c * 4 + 3];
            out[c * NPIX + pid] = o;
        }
    }
}

} // namespace

extern "C" void kernel_launch(void* const* d_in, const int* in_sizes, int n_in,
                              void* d_out, int out_size, void* d_ws, size_t ws_size,
                              hipStream_t stream)
{
    const float4* noisy = (const float4*)d_in[0];
    const float4* guid  = (const float4*)d_in[1];
    const float4* est   = (const float4*)d_in[2];
    const float4* var   = (const float4*)d_in[3];
    float4* out = (float4*)d_out;

    statden<<<NPIX / 64, NTHR, 0, stream>>>(noisy, guid, est, var, out);
}